// Round 6
// baseline (1308.009 us; speedup 1.0000x reference)
//
#include <hip/hip_runtime.h>
#include <hip/hip_fp16.h>
#include <math.h>

// dst-CSR built with ZERO N-wide passes: bucket_hist/scan/binsort/fill2.
// gemm_k: no W staging (L1-resident), 64-row x tile; slice-major fp16 epilogue.
// prop_k (r6): feature-sliced (4 x 32 B, per-slice 3.2 MB -> L2-resident via
//   blockIdx&7 XCD pinning) combining the proven halves of r4/r5:
//     - INDEX-ordered rows (r4): cols stream sequentially, state stays
//       L2-resident, FETCH floor ~80 MB (r5's degree-sort scattered cols ->
//       FETCH 180 MB; removed)
//     - NON-TEMPORAL cols (r4): 51 MB/pass cols stream bypasses L2, never
//       thrashes the 3.2 MB state slice
//     - distance-2 register pipeline on cols (r5 deepened): ~1000 SIMD-cycles
//       between nt-load and use -> HBM latency fully hidden (r4's failure was
//       nt at distance-0)
//     - 16 edges/row/iter = 2 independent gather chains per lane

#define BSH 8        // 256 dsts per bucket (CSR build)
#define NSL 4        // feature slices; per-slice row = 16 fp16 = 32 B

typedef _Float16 h2_t __attribute__((ext_vector_type(2)));
union U16 { uint4 u; h2_t h[4]; };

// ---------------- small utils ----------------

__global__ void zero_i32(int* __restrict__ p, int n) {
    int i = blockIdx.x * blockDim.x + threadIdx.x;
    if (i < n) p[i] = 0;
}

// zero dummy row N of each slice of the three gather buffers
__global__ void zero_dummy(__half2* __restrict__ b0, __half2* __restrict__ b1,
                           __half2* __restrict__ b2, int N) {
    int t = threadIdx.x;
    if (t >= 96) return;              // 3 buffers x 4 slices x 8 half2
    __half2* b = (t < 32) ? b0 : (t < 64) ? b1 : b2;
    int r = t & 31;
    int s = r >> 3, h = r & 7;
    b[((size_t)s * (N + 1) + N) * 8 + h] = __floats2half2_rn(0.f, 0.f);
}

// ---------------- bucket histogram (LDS-aggregated) ----------------

__global__ void __launch_bounds__(256) bucket_hist_k(const int* __restrict__ dst, int E,
                                                     int* __restrict__ bktcnt) {
    __shared__ int hist[400];
    int t = threadIdx.x;
    for (int i = t; i < 400; i += 256) hist[i] = 0;
    __syncthreads();
    int e0 = blockIdx.x * 4096 + t;
#pragma unroll
    for (int i = 0; i < 16; ++i) {
        int e = e0 + i * 256;
        if (e < E) atomicAdd(&hist[dst[e] >> BSH], 1);
    }
    __syncthreads();
    for (int b = t; b < 400; b += 256) {
        int c = hist[b];
        if (c > 0) atomicAdd(&bktcnt[b], c);
    }
}

// ---------------- 1-block scan of bucket totals -> bases + padded cursors ----------------

__global__ void bucket_scan_k(const int* __restrict__ bktcnt, int nb, int E,
                              int* __restrict__ bktbase, int* __restrict__ bktcur) {
    __shared__ int s[256];
    int t = threadIdx.x;
    int C = (nb + 255) / 256;            // <= 8
    int b0 = t * C;
    int loc[8]; int sum = 0;
    for (int i = 0; i < C; ++i) {
        int v = (b0 + i < nb) ? bktcnt[b0 + i] : 0;
        loc[i] = sum; sum += v;
    }
    s[t] = sum; __syncthreads();
    for (int off = 1; off < 256; off <<= 1) {
        int v = (t >= off) ? s[t - off] : 0;
        __syncthreads();
        s[t] += v;
        __syncthreads();
    }
    int excl = s[t] - sum;
    for (int i = 0; i < C; ++i)
        if (b0 + i < nb) {
            int e0 = excl + loc[i];
            bktbase[b0 + i] = e0;
            bktcur[(b0 + i) * 16] = e0;  // 64B-padded cursor
        }
    if (t == 0) bktbase[nb] = E;
}

// ---------------- bin edges by bucket (dst>>8), contiguous runs ----------------

__global__ void __launch_bounds__(256) binsort_k(const int* __restrict__ src,
                                                 const int* __restrict__ dst, int E,
                                                 int* __restrict__ bktcur,  // padded x16
                                                 unsigned* __restrict__ binned) {
    __shared__ int hist[400], gbase[400], lcur[400];
    int t = threadIdx.x;
    for (int i = t; i < 400; i += 256) { hist[i] = 0; lcur[i] = 0; }
    __syncthreads();

    int e0 = blockIdx.x * 4096 + t;
    unsigned rec[16]; int bk[16];
#pragma unroll
    for (int i = 0; i < 16; ++i) {
        int e = e0 + i * 256;
        if (e < E) {
            int s = src[e], d = dst[e];
            bk[i]  = d >> BSH;
            rec[i] = ((unsigned)s << BSH) | (unsigned)(d & 255);
            atomicAdd(&hist[bk[i]], 1);
        } else bk[i] = -1;
    }
    __syncthreads();
    for (int b = t; b < 400; b += 256) {
        int c = hist[b];
        if (c > 0) gbase[b] = atomicAdd(&bktcur[b * 16], c);
    }
    __syncthreads();
#pragma unroll
    for (int i = 0; i < 16; ++i) {
        if (bk[i] >= 0) {
            int loc = atomicAdd(&lcur[bk[i]], 1);
            binned[gbase[bk[i]] + loc] = rec[i];
        }
    }
}

// ---------------- per-bucket: degrees + rowptr + dinv + col scatter ----------------

__global__ void __launch_bounds__(256) fill2_k(const unsigned* __restrict__ binned,
                                               const int* __restrict__ bktbase,
                                               int N, int E, int NB,
                                               int* __restrict__ rowptr,
                                               float* __restrict__ dinv,
                                               int* __restrict__ col) {
    __shared__ int cnt[256], excl[256], lcur[256];
    int b = blockIdx.x, t = threadIdx.x;
    int beg = bktbase[b], end = bktbase[b + 1];
    cnt[t] = 0;
    __syncthreads();
    for (int i = beg + t; i < end; i += 256)
        atomicAdd(&cnt[binned[i] & 255u], 1);
    __syncthreads();
    int v = cnt[t];
    excl[t] = v;
    __syncthreads();
    for (int off = 1; off < 256; off <<= 1) {
        int u = (t >= off) ? excl[t - off] : 0;
        __syncthreads();
        excl[t] += u;
        __syncthreads();
    }
    int ex = excl[t] - v;                // exclusive prefix within bucket
    lcur[t] = ex;
    int d = (b << BSH) + t;
    if (d < N) {
        rowptr[d] = beg + ex;            // coalesced
        dinv[d] = rsqrtf((float)(v + 1));  // +1 self-loop
    }
    if (b == NB - 1 && t == 0) rowptr[N] = E;
    __syncthreads();
    for (int i = beg + t; i < end; i += 256) {
        unsigned r = binned[i];
        int loc = atomicAdd(&lcur[r & 255u], 1);
        col[beg + loc] = (int)(r >> BSH);   // scatter inside this bucket's segment
    }
}

// ---------------- g0 = x @ W : 64-row tile, W from global (L1-resident) ----------------
// Slice-major epilogue: feature j lives in slice j/16 at offset j%16.
// g0t[slice][n] = g0 (teleport, unscaled); g0h[slice][n] = dinv[n]*g0 (state).

__global__ void __launch_bounds__(256) gemm_k(const float* __restrict__ x,
                                              const float* __restrict__ W,
                                              const float* __restrict__ dinv,
                                              __half2* __restrict__ g0t,
                                              __half2* __restrict__ g0h, int N) {
    __shared__ float xs[64 * 133];        // ~34 KB -> 4 blocks/CU
    int t = threadIdx.x;
    int n0 = blockIdx.x * 64;
    for (int f = t; f < 64 * 32; f += 256) {
        int r = f >> 5, c4 = f & 31;
        int n = n0 + r;
        float4 v = (n < N) ? ((const float4*)x)[(size_t)n * 32 + c4]
                           : make_float4(0.f, 0.f, 0.f, 0.f);
        float* dp = &xs[r * 133 + c4 * 4];
        dp[0] = v.x; dp[1] = v.y; dp[2] = v.z; dp[3] = v.w;
    }
    __syncthreads();
    int tr = t & 15, tc = t >> 4;
    int r0 = tc * 4;
    const float4* W4 = (const float4*)W;  // 32 KB total -> L1-resident
    float acc[4][4] = {};
#pragma unroll 8
    for (int k = 0; k < 128; ++k) {
        float4 wv = W4[k * 16 + tr];      // 256 B/k, broadcast across tc, L1 hit
#pragma unroll
        for (int i = 0; i < 4; ++i) {
            float xv = xs[(r0 + i) * 133 + k];
            acc[i][0] += xv * wv.x; acc[i][1] += xv * wv.y;
            acc[i][2] += xv * wv.z; acc[i][3] += xv * wv.w;
        }
    }
    int slice = tr >> 2;                  // j0 = tr*4 -> slice j0/16
    int o = (tr & 3) * 2;                 // half2 offset within the 32-B slice row
#pragma unroll
    for (int i = 0; i < 4; ++i) {
        int n = n0 + r0 + i;
        if (n < N) {
            float dn = dinv[n];
            size_t rb = ((size_t)slice * (N + 1) + n) * 8;
            g0t[rb + o]     = __floats2half2_rn(acc[i][0], acc[i][1]);
            g0t[rb + o + 1] = __floats2half2_rn(acc[i][2], acc[i][3]);
            g0h[rb + o]     = __floats2half2_rn(acc[i][0] * dn, acc[i][1] * dn);
            g0h[rb + o + 1] = __floats2half2_rn(acc[i][2] * dn, acc[i][3] * dn);
        }
    }
}

// ---------------- propagation: 4-slice, XCD-pinned, index-ordered ----------------
// Grid = pairs*8; xcd = bid&7; slice = xcd>>1; seq = (bid>>3)*2 + (xcd&1).
// Block = 4 waves x 4 CONSECUTIVE rows of one slice (index order -> cols
// stream sequentially). Wave lanes: r = lane>>4 (row), e = (lane>>1)&7
// (edge slot), q = lane&1 (16-B half of the 32-B slice row).
// cols: NON-TEMPORAL (protect L2-resident state) at prefetch distance 2.

__global__ void __launch_bounds__(256) prop_k(const __half2* __restrict__ gin,
                                              const __half2* __restrict__ g0t,
                                              __half2* __restrict__ gout,
                                              float* __restrict__ outf,
                                              const int* __restrict__ rowptr,
                                              const int* __restrict__ cols,
                                              const float* __restrict__ dinv,
                                              const float* __restrict__ bias,
                                              int N, int nseq, int final_step) {
    int bid = blockIdx.x;
    int xcd = bid & 7;
    int slice = xcd >> 1;
    int seq = (bid >> 3) * 2 + (xcd & 1);
    if (seq >= nseq) return;

    int lane = threadIdx.x & 63;
    int wid  = threadIdx.x >> 6;
    int r = lane >> 4;          // row within wave
    int e = (lane >> 1) & 7;    // edge slot
    int q = lane & 1;           // 16-B half
    unsigned qo = (unsigned)(q << 4);

    int gw  = seq * 16 + wid * 4 + r;
    int gcl = (gw < N) ? gw : 0;        // safe row for scalar reads

    size_t srow = (size_t)slice * (N + 1);
    const char* gb = (const char*)gin + srow * 32;   // slice base (SGPR)

    int beg = rowptr[gcl];
    int deg = (gw < N) ? (rowptr[gcl + 1] - beg) : 0;
    float di = dinv[gcl];

    // hoisted self + teleport 16-B segments (overlap with gather latency)
    U16 gi;  gi.u  = *(const uint4*)(gb + (((unsigned)gcl << 5) | qo));
    U16 g0v; g0v.u = *(const uint4*)((const char*)g0t + (srow + gcl) * 32 + qo);

    // wave max degree (deg uniform within each 16-lane row group)
    int md = deg;
    md = max(md, __shfl_xor(md, 16, 64));
    md = max(md, __shfl_xor(md, 32, 64));

    const h2_t SEL_LO = {(_Float16)1.f, (_Float16)0.f};
    const h2_t SEL_HI = {(_Float16)0.f, (_Float16)1.f};
    float a[8] = {};   // this lane's 8 feature accumulators (its q-half)

    if (md > 0) {
        // distance-2 cols pipeline (nt: bypass L2, latency hidden by 2 iters)
        int c0 = __builtin_nontemporal_load(cols + beg + (e      < deg ? e      : 0));
        int c1 = __builtin_nontemporal_load(cols + beg + (8 + e  < deg ? 8 + e  : 0));
        int c2 = (16 < md) ? __builtin_nontemporal_load(cols + beg + (16 + e < deg ? 16 + e : 0)) : c0;
        int c3 = (16 < md) ? __builtin_nontemporal_load(cols + beg + (24 + e < deg ? 24 + e : 0)) : c1;
        for (int base = 0; base < md; base += 16) {
            int cc0 = (base + e     < deg) ? c0 : N;   // dummy zero row pad
            int cc1 = (base + 8 + e < deg) ? c1 : N;
            c0 = c2; c1 = c3;
            int nb = base + 32;
            if (nb < md) {                             // uniform branch
                c2 = __builtin_nontemporal_load(cols + beg + (nb + e     < deg ? nb + e     : 0));
                c3 = __builtin_nontemporal_load(cols + beg + (nb + 8 + e < deg ? nb + 8 + e : 0));
            }
            U16 v0, v1;
            v0.u = *(const uint4*)(gb + (((unsigned)cc0 << 5) | qo));
            v1.u = *(const uint4*)(gb + (((unsigned)cc1 << 5) | qo));
#pragma unroll
            for (int u = 0; u < 4; ++u) {
                a[2 * u]     = __builtin_amdgcn_fdot2(v0.h[u], SEL_LO, a[2 * u],     false);
                a[2 * u + 1] = __builtin_amdgcn_fdot2(v0.h[u], SEL_HI, a[2 * u + 1], false);
            }
#pragma unroll
            for (int u = 0; u < 4; ++u) {
                a[2 * u]     = __builtin_amdgcn_fdot2(v1.h[u], SEL_LO, a[2 * u],     false);
                a[2 * u + 1] = __builtin_amdgcn_fdot2(v1.h[u], SEL_HI, a[2 * u + 1], false);
            }
        }
    }

    // reduce across the 8 edge slots (lane bits 1..3; row & q preserved)
#pragma unroll
    for (int off = 2; off <= 8; off <<= 1) {
#pragma unroll
        for (int u = 0; u < 8; ++u) a[u] += __shfl_xor(a[u], off, 64);
    }

    if ((lane & 14) == 0 && gw < N) {   // lanes (r,q): row gw, features [8q,8q+8) of slice
        float rr[8];
#pragma unroll
        for (int u = 0; u < 4; ++u) {
            float2 gf = __half22float2(*(__half2*)&gi.h[u]);
            float2 g0 = __half22float2(*(__half2*)&g0v.h[u]);
            rr[2 * u]     = 0.9f * di * (a[2 * u]     + gf.x) + 0.1f * g0.x;
            rr[2 * u + 1] = 0.9f * di * (a[2 * u + 1] + gf.y) + 0.1f * g0.y;
        }
        if (final_step) {
            float4 b0 = ((const float4*)bias)[slice * 4 + q * 2];
            float4 b1 = ((const float4*)bias)[slice * 4 + q * 2 + 1];
            float4* op = (float4*)(outf + (size_t)gw * 64 + slice * 16 + q * 8);
            op[0] = make_float4(rr[0] + b0.x, rr[1] + b0.y, rr[2] + b0.z, rr[3] + b0.w);
            op[1] = make_float4(rr[4] + b1.x, rr[5] + b1.y, rr[6] + b1.z, rr[7] + b1.w);
        } else {
            U16 o;
#pragma unroll
            for (int u = 0; u < 4; ++u) {
                __half2 h = __floats2half2_rn(di * rr[2 * u], di * rr[2 * u + 1]);
                o.h[u] = *(h2_t*)&h;
            }
            *(uint4*)((char*)gout + (srow + gw) * 32 + qo) = o.u;
        }
    }
}

// ---------------- launch ----------------

extern "C" void kernel_launch(void* const* d_in, const int* in_sizes, int n_in,
                              void* d_out, int out_size, void* d_ws, size_t ws_size,
                              hipStream_t stream) {
    const float* x  = (const float*)d_in[0];
    const int*   ei = (const int*)d_in[1];
    const float* W  = (const float*)d_in[2];
    const float* b  = (const float*)d_in[3];
    float* out = (float*)d_out;

    const int N = in_sizes[0] / 128;
    const int E = in_sizes[1] / 2;
    const int* src = ei;
    const int* dst = ei + E;
    const int NB = (N + 255) >> BSH;     // buckets of 256 dsts

    char* w = (char*)d_ws;
    size_t off = 0;
    auto alloc = [&](size_t bytes) -> void* {
        void* p = w + off;
        off += (bytes + 255) & ~(size_t)255;
        return p;
    };
    // slice-major fp16 state: NSL slices x (N+1) rows x 32 B
    const size_t fp16buf = (size_t)NSL * (N + 1) * 32;
    __half2*  g0h    = (__half2*) alloc(fp16buf);   // dinv-scaled initial state
    __half2*  bufA   = (__half2*) alloc(fp16buf);
    __half2*  bufB   = (__half2*) alloc(fp16buf);
    __half2*  g0t    = (__half2*) alloc(fp16buf);   // teleport term (unscaled)
    int*      cols   = (int*)     alloc((size_t)E * 4);
    unsigned* binned = (unsigned*)alloc((size_t)E * 4);
    int*      rowptr = (int*)     alloc((size_t)(N + 1) * 4);
    int*      bktcnt = (int*)     alloc((size_t)NB * 4);
    int*      bktbase= (int*)     alloc((size_t)(NB + 1) * 4);
    int*      bktcur = (int*)     alloc((size_t)NB * 16 * 4);    // 64B-padded
    float*    dinvv  = (float*)   alloc((size_t)N * 4);

    const int nblkB = (E + 4095) / 4096;

    // ---- build dst-CSR: bucket hist -> scan -> binsort -> per-bucket fill ----
    zero_i32<<<(NB + 255) / 256, 256, 0, stream>>>(bktcnt, NB);
    bucket_hist_k<<<nblkB, 256, 0, stream>>>(dst, E, bktcnt);
    zero_dummy<<<1, 96, 0, stream>>>(g0h, bufA, bufB, N);
    bucket_scan_k<<<1, 256, 0, stream>>>(bktcnt, NB, E, bktbase, bktcur);
    binsort_k<<<nblkB, 256, 0, stream>>>(src, dst, E, bktcur, binned);
    fill2_k<<<NB, 256, 0, stream>>>(binned, bktbase, N, E, NB, rowptr, dinvv, cols);

    // g0 = x @ W (propagation commutes with the linear head)
    gemm_k<<<(N + 63) / 64, 256, 0, stream>>>(x, W, dinvv, g0t, g0h, N);

    // K = 10 APPNP steps, fp16 ping-pong; last step writes fp32 d_out (+bias)
    const int nseq  = (N + 15) / 16;          // 16 rows per block (4 waves x 4)
    const int pairs = (nseq + 1) / 2;
    const int grid  = pairs * 8;              // 8 XCD lanes (4 slices x 2)
    const __half2* gin = g0h;
    __half2* pp[2] = {bufA, bufB};
    for (int k = 0; k < 10; ++k) {
        const bool fin = (k == 9);
        __half2* gout = pp[k & 1];
        prop_k<<<grid, 256, 0, stream>>>(gin, g0t, gout, out, rowptr, cols,
                                         dinvv, b, N, nseq, fin ? 1 : 0);
        gin = gout;
    }
}

// Round 7
// 917.763 us; speedup vs baseline: 1.4252x; 1.4252x over previous
//
#include <hip/hip_runtime.h>
#include <hip/hip_fp16.h>
#include <math.h>

// dst-CSR built with ZERO N-wide passes: bucket_hist/scan/binsort/fill2.
// gemm_k: no W staging (L1-resident), 64-row x tile; slice-major fp16 epilogue.
// prop_k (r7): feature-sliced (4 x 32 B, per-slice 3.2 MB -> L2-resident via
//   blockIdx&7 XCD pinning), CACHED cols (r6's nt loads had 900-cyc HBM
//   latency coupled to the gathers by in-order vmcnt counting -> 32% VALU;
//   r3 proved cached+index-order keeps FETCH at the ~75 MB floor), index
//   order, distance-2 cols register pipeline, pre-scaled cols (col<<5),
//   clamped unconditional prefetch (no selects/branches on the cols path).

#define BSH 8        // 256 dsts per bucket (CSR build)
#define NSL 4        // feature slices; per-slice row = 16 fp16 = 32 B

typedef _Float16 h2_t __attribute__((ext_vector_type(2)));
union U16 { uint4 u; h2_t h[4]; };

// ---------------- small utils ----------------

__global__ void zero_i32(int* __restrict__ p, int n) {
    int i = blockIdx.x * blockDim.x + threadIdx.x;
    if (i < n) p[i] = 0;
}

// zero dummy row N of each slice of the three gather buffers
__global__ void zero_dummy(__half2* __restrict__ b0, __half2* __restrict__ b1,
                           __half2* __restrict__ b2, int N) {
    int t = threadIdx.x;
    if (t >= 96) return;              // 3 buffers x 4 slices x 8 half2
    __half2* b = (t < 32) ? b0 : (t < 64) ? b1 : b2;
    int r = t & 31;
    int s = r >> 3, h = r & 7;
    b[((size_t)s * (N + 1) + N) * 8 + h] = __floats2half2_rn(0.f, 0.f);
}

// ---------------- bucket histogram (LDS-aggregated) ----------------

__global__ void __launch_bounds__(256) bucket_hist_k(const int* __restrict__ dst, int E,
                                                     int* __restrict__ bktcnt) {
    __shared__ int hist[400];
    int t = threadIdx.x;
    for (int i = t; i < 400; i += 256) hist[i] = 0;
    __syncthreads();
    int e0 = blockIdx.x * 4096 + t;
#pragma unroll
    for (int i = 0; i < 16; ++i) {
        int e = e0 + i * 256;
        if (e < E) atomicAdd(&hist[dst[e] >> BSH], 1);
    }
    __syncthreads();
    for (int b = t; b < 400; b += 256) {
        int c = hist[b];
        if (c > 0) atomicAdd(&bktcnt[b], c);
    }
}

// ---------------- 1-block scan of bucket totals -> bases + padded cursors ----------------

__global__ void bucket_scan_k(const int* __restrict__ bktcnt, int nb, int E,
                              int* __restrict__ bktbase, int* __restrict__ bktcur) {
    __shared__ int s[256];
    int t = threadIdx.x;
    int C = (nb + 255) / 256;            // <= 8
    int b0 = t * C;
    int loc[8]; int sum = 0;
    for (int i = 0; i < C; ++i) {
        int v = (b0 + i < nb) ? bktcnt[b0 + i] : 0;
        loc[i] = sum; sum += v;
    }
    s[t] = sum; __syncthreads();
    for (int off = 1; off < 256; off <<= 1) {
        int v = (t >= off) ? s[t - off] : 0;
        __syncthreads();
        s[t] += v;
        __syncthreads();
    }
    int excl = s[t] - sum;
    for (int i = 0; i < C; ++i)
        if (b0 + i < nb) {
            int e0 = excl + loc[i];
            bktbase[b0 + i] = e0;
            bktcur[(b0 + i) * 16] = e0;  // 64B-padded cursor
        }
    if (t == 0) bktbase[nb] = E;
}

// ---------------- bin edges by bucket (dst>>8), contiguous runs ----------------

__global__ void __launch_bounds__(256) binsort_k(const int* __restrict__ src,
                                                 const int* __restrict__ dst, int E,
                                                 int* __restrict__ bktcur,  // padded x16
                                                 unsigned* __restrict__ binned) {
    __shared__ int hist[400], gbase[400], lcur[400];
    int t = threadIdx.x;
    for (int i = t; i < 400; i += 256) { hist[i] = 0; lcur[i] = 0; }
    __syncthreads();

    int e0 = blockIdx.x * 4096 + t;
    unsigned rec[16]; int bk[16];
#pragma unroll
    for (int i = 0; i < 16; ++i) {
        int e = e0 + i * 256;
        if (e < E) {
            int s = src[e], d = dst[e];
            bk[i]  = d >> BSH;
            rec[i] = ((unsigned)s << BSH) | (unsigned)(d & 255);
            atomicAdd(&hist[bk[i]], 1);
        } else bk[i] = -1;
    }
    __syncthreads();
    for (int b = t; b < 400; b += 256) {
        int c = hist[b];
        if (c > 0) gbase[b] = atomicAdd(&bktcur[b * 16], c);
    }
    __syncthreads();
#pragma unroll
    for (int i = 0; i < 16; ++i) {
        if (bk[i] >= 0) {
            int loc = atomicAdd(&lcur[bk[i]], 1);
            binned[gbase[bk[i]] + loc] = rec[i];
        }
    }
}

// ---------------- per-bucket: degrees + rowptr + dinv + col scatter ----------------
// cols stored PRE-SCALED (col<<5 = byte offset of the 32-B slice row).

__global__ void __launch_bounds__(256) fill2_k(const unsigned* __restrict__ binned,
                                               const int* __restrict__ bktbase,
                                               int N, int E, int NB,
                                               int* __restrict__ rowptr,
                                               float* __restrict__ dinv,
                                               int* __restrict__ col) {
    __shared__ int cnt[256], excl[256], lcur[256];
    int b = blockIdx.x, t = threadIdx.x;
    int beg = bktbase[b], end = bktbase[b + 1];
    cnt[t] = 0;
    __syncthreads();
    for (int i = beg + t; i < end; i += 256)
        atomicAdd(&cnt[binned[i] & 255u], 1);
    __syncthreads();
    int v = cnt[t];
    excl[t] = v;
    __syncthreads();
    for (int off = 1; off < 256; off <<= 1) {
        int u = (t >= off) ? excl[t - off] : 0;
        __syncthreads();
        excl[t] += u;
        __syncthreads();
    }
    int ex = excl[t] - v;                // exclusive prefix within bucket
    lcur[t] = ex;
    int d = (b << BSH) + t;
    if (d < N) {
        rowptr[d] = beg + ex;            // coalesced
        dinv[d] = rsqrtf((float)(v + 1));  // +1 self-loop
    }
    if (b == NB - 1 && t == 0) rowptr[N] = E;
    __syncthreads();
    for (int i = beg + t; i < end; i += 256) {
        unsigned r = binned[i];
        int loc = atomicAdd(&lcur[r & 255u], 1);
        col[beg + loc] = (int)(r >> BSH) << 5;   // pre-scaled byte offset
    }
}

// ---------------- g0 = x @ W : 64-row tile, W from global (L1-resident) ----------------
// Slice-major epilogue: feature j lives in slice j/16 at offset j%16.
// g0t[slice][n] = g0 (teleport, unscaled); g0h[slice][n] = dinv[n]*g0 (state).

__global__ void __launch_bounds__(256) gemm_k(const float* __restrict__ x,
                                              const float* __restrict__ W,
                                              const float* __restrict__ dinv,
                                              __half2* __restrict__ g0t,
                                              __half2* __restrict__ g0h, int N) {
    __shared__ float xs[64 * 133];        // ~34 KB -> 4 blocks/CU
    int t = threadIdx.x;
    int n0 = blockIdx.x * 64;
    for (int f = t; f < 64 * 32; f += 256) {
        int r = f >> 5, c4 = f & 31;
        int n = n0 + r;
        float4 v = (n < N) ? ((const float4*)x)[(size_t)n * 32 + c4]
                           : make_float4(0.f, 0.f, 0.f, 0.f);
        float* dp = &xs[r * 133 + c4 * 4];
        dp[0] = v.x; dp[1] = v.y; dp[2] = v.z; dp[3] = v.w;
    }
    __syncthreads();
    int tr = t & 15, tc = t >> 4;
    int r0 = tc * 4;
    const float4* W4 = (const float4*)W;  // 32 KB total -> L1-resident
    float acc[4][4] = {};
#pragma unroll 8
    for (int k = 0; k < 128; ++k) {
        float4 wv = W4[k * 16 + tr];      // 256 B/k, broadcast across tc, L1 hit
#pragma unroll
        for (int i = 0; i < 4; ++i) {
            float xv = xs[(r0 + i) * 133 + k];
            acc[i][0] += xv * wv.x; acc[i][1] += xv * wv.y;
            acc[i][2] += xv * wv.z; acc[i][3] += xv * wv.w;
        }
    }
    int slice = tr >> 2;                  // j0 = tr*4 -> slice j0/16
    int o = (tr & 3) * 2;                 // half2 offset within the 32-B slice row
#pragma unroll
    for (int i = 0; i < 4; ++i) {
        int n = n0 + r0 + i;
        if (n < N) {
            float dn = dinv[n];
            size_t rb = ((size_t)slice * (N + 1) + n) * 8;
            g0t[rb + o]     = __floats2half2_rn(acc[i][0], acc[i][1]);
            g0t[rb + o + 1] = __floats2half2_rn(acc[i][2], acc[i][3]);
            g0h[rb + o]     = __floats2half2_rn(acc[i][0] * dn, acc[i][1] * dn);
            g0h[rb + o + 1] = __floats2half2_rn(acc[i][2] * dn, acc[i][3] * dn);
        }
    }
}

// ---------------- propagation: 4-slice, XCD-pinned, index-ordered ----------------
// Grid = pairs*8; xcd = bid&7; slice = xcd>>1; seq = (bid>>3)*2 + (xcd&1).
// Block = 4 waves x 4 CONSECUTIVE rows of one slice. Wave lanes: r = lane>>4
// (row), e = (lane>>1)&7 (edge slot), q = lane&1 (16-B half of the row).
// cols: CACHED, distance-2 register pipeline, clamped unconditional prefetch.

__global__ void __launch_bounds__(256) prop_k(const __half2* __restrict__ gin,
                                              const __half2* __restrict__ g0t,
                                              __half2* __restrict__ gout,
                                              float* __restrict__ outf,
                                              const int* __restrict__ rowptr,
                                              const int* __restrict__ cols,
                                              const float* __restrict__ dinv,
                                              const float* __restrict__ bias,
                                              int N, int E, int nseq, int final_step) {
    int bid = blockIdx.x;
    int xcd = bid & 7;
    int slice = xcd >> 1;
    int seq = (bid >> 3) * 2 + (xcd & 1);
    if (seq >= nseq) return;

    int lane = threadIdx.x & 63;
    int wid  = threadIdx.x >> 6;
    int r = lane >> 4;          // row within wave
    int e = (lane >> 1) & 7;    // edge slot
    int q = lane & 1;           // 16-B half
    unsigned qo = (unsigned)(q << 4);

    int gw  = seq * 16 + wid * 4 + r;
    int gcl = (gw < N) ? gw : 0;        // safe row for scalar reads

    size_t srow = (size_t)slice * (N + 1);
    const char* gb = (const char*)gin + srow * 32;   // slice base (SGPR)

    int beg = rowptr[gcl];
    int deg = (gw < N) ? (rowptr[gcl + 1] - beg) : 0;
    float di = dinv[gcl];

    // hoisted self + teleport 16-B segments (overlap with gather latency)
    U16 gi;  gi.u  = *(const uint4*)(gb + (((unsigned)gcl << 5) | qo));
    U16 g0v; g0v.u = *(const uint4*)((const char*)g0t + (srow + gcl) * 32 + qo);

    // wave max degree (deg uniform within each 16-lane row group)
    int md = deg;
    md = max(md, __shfl_xor(md, 16, 64));
    md = max(md, __shfl_xor(md, 32, 64));

    const h2_t SEL_LO = {(_Float16)1.f, (_Float16)0.f};
    const h2_t SEL_HI = {(_Float16)0.f, (_Float16)1.f};
    float a[8] = {};   // this lane's 8 feature accumulators (its q-half)
    const int DUMMY = N << 5;           // pre-scaled dummy row offset
    const int emax  = E - 1;

    if (md > 0) {
        // distance-2 cols pipeline; clamped indices, masking happens at use
        int i0 = beg + e, i1 = beg + 8 + e;
        int c0 = cols[min(i0,      emax)];
        int c1 = cols[min(i1,      emax)];
        int c2 = cols[min(i0 + 16, emax)];
        int c3 = cols[min(i1 + 16, emax)];
        for (int base = 0; base < md; base += 16) {
            int cc0 = (base + e     < deg) ? c0 : DUMMY;
            int cc1 = (base + 8 + e < deg) ? c1 : DUMMY;
            c0 = c2; c1 = c3;
            U16 v0, v1;
            v0.u = *(const uint4*)(gb + (unsigned)(cc0 | (int)qo));
            v1.u = *(const uint4*)(gb + (unsigned)(cc1 | (int)qo));
            int nb = base + 32;
            if (nb < md) {                             // wave-uniform branch
                c2 = cols[min(i0 + nb, emax)];
                c3 = cols[min(i1 + nb, emax)];
            }
#pragma unroll
            for (int u = 0; u < 4; ++u) {
                a[2 * u]     = __builtin_amdgcn_fdot2(v0.h[u], SEL_LO, a[2 * u],     false);
                a[2 * u + 1] = __builtin_amdgcn_fdot2(v0.h[u], SEL_HI, a[2 * u + 1], false);
            }
#pragma unroll
            for (int u = 0; u < 4; ++u) {
                a[2 * u]     = __builtin_amdgcn_fdot2(v1.h[u], SEL_LO, a[2 * u],     false);
                a[2 * u + 1] = __builtin_amdgcn_fdot2(v1.h[u], SEL_HI, a[2 * u + 1], false);
            }
        }
    }

    // reduce across the 8 edge slots (lane bits 1..3; row & q preserved)
#pragma unroll
    for (int off = 2; off <= 8; off <<= 1) {
#pragma unroll
        for (int u = 0; u < 8; ++u) a[u] += __shfl_xor(a[u], off, 64);
    }

    if ((lane & 14) == 0 && gw < N) {   // lanes (r,q): row gw, features [8q,8q+8) of slice
        float rr[8];
#pragma unroll
        for (int u = 0; u < 4; ++u) {
            float2 gf = __half22float2(*(__half2*)&gi.h[u]);
            float2 g0 = __half22float2(*(__half2*)&g0v.h[u]);
            rr[2 * u]     = 0.9f * di * (a[2 * u]     + gf.x) + 0.1f * g0.x;
            rr[2 * u + 1] = 0.9f * di * (a[2 * u + 1] + gf.y) + 0.1f * g0.y;
        }
        if (final_step) {
            float4 b0 = ((const float4*)bias)[slice * 4 + q * 2];
            float4 b1 = ((const float4*)bias)[slice * 4 + q * 2 + 1];
            float4* op = (float4*)(outf + (size_t)gw * 64 + slice * 16 + q * 8);
            op[0] = make_float4(rr[0] + b0.x, rr[1] + b0.y, rr[2] + b0.z, rr[3] + b0.w);
            op[1] = make_float4(rr[4] + b1.x, rr[5] + b1.y, rr[6] + b1.z, rr[7] + b1.w);
        } else {
            U16 o;
#pragma unroll
            for (int u = 0; u < 4; ++u) {
                __half2 h = __floats2half2_rn(di * rr[2 * u], di * rr[2 * u + 1]);
                o.h[u] = *(h2_t*)&h;
            }
            *(uint4*)((char*)gout + (srow + gw) * 32 + qo) = o.u;
        }
    }
}

// ---------------- launch ----------------

extern "C" void kernel_launch(void* const* d_in, const int* in_sizes, int n_in,
                              void* d_out, int out_size, void* d_ws, size_t ws_size,
                              hipStream_t stream) {
    const float* x  = (const float*)d_in[0];
    const int*   ei = (const int*)d_in[1];
    const float* W  = (const float*)d_in[2];
    const float* b  = (const float*)d_in[3];
    float* out = (float*)d_out;

    const int N = in_sizes[0] / 128;
    const int E = in_sizes[1] / 2;
    const int* src = ei;
    const int* dst = ei + E;
    const int NB = (N + 255) >> BSH;     // buckets of 256 dsts

    char* w = (char*)d_ws;
    size_t off = 0;
    auto alloc = [&](size_t bytes) -> void* {
        void* p = w + off;
        off += (bytes + 255) & ~(size_t)255;
        return p;
    };
    // slice-major fp16 state: NSL slices x (N+1) rows x 32 B
    const size_t fp16buf = (size_t)NSL * (N + 1) * 32;
    __half2*  g0h    = (__half2*) alloc(fp16buf);   // dinv-scaled initial state
    __half2*  bufA   = (__half2*) alloc(fp16buf);
    __half2*  bufB   = (__half2*) alloc(fp16buf);
    __half2*  g0t    = (__half2*) alloc(fp16buf);   // teleport term (unscaled)
    int*      cols   = (int*)     alloc((size_t)E * 4);
    unsigned* binned = (unsigned*)alloc((size_t)E * 4);
    int*      rowptr = (int*)     alloc((size_t)(N + 1) * 4);
    int*      bktcnt = (int*)     alloc((size_t)NB * 4);
    int*      bktbase= (int*)     alloc((size_t)(NB + 1) * 4);
    int*      bktcur = (int*)     alloc((size_t)NB * 16 * 4);    // 64B-padded
    float*    dinvv  = (float*)   alloc((size_t)N * 4);

    const int nblkB = (E + 4095) / 4096;

    // ---- build dst-CSR: bucket hist -> scan -> binsort -> per-bucket fill ----
    zero_i32<<<(NB + 255) / 256, 256, 0, stream>>>(bktcnt, NB);
    bucket_hist_k<<<nblkB, 256, 0, stream>>>(dst, E, bktcnt);
    zero_dummy<<<1, 96, 0, stream>>>(g0h, bufA, bufB, N);
    bucket_scan_k<<<1, 256, 0, stream>>>(bktcnt, NB, E, bktbase, bktcur);
    binsort_k<<<nblkB, 256, 0, stream>>>(src, dst, E, bktcur, binned);
    fill2_k<<<NB, 256, 0, stream>>>(binned, bktbase, N, E, NB, rowptr, dinvv, cols);

    // g0 = x @ W (propagation commutes with the linear head)
    gemm_k<<<(N + 63) / 64, 256, 0, stream>>>(x, W, dinvv, g0t, g0h, N);

    // K = 10 APPNP steps, fp16 ping-pong; last step writes fp32 d_out (+bias)
    const int nseq  = (N + 15) / 16;          // 16 rows per block (4 waves x 4)
    const int pairs = (nseq + 1) / 2;
    const int grid  = pairs * 8;              // 8 XCD lanes (4 slices x 2)
    const __half2* gin = g0h;
    __half2* pp[2] = {bufA, bufB};
    for (int k = 0; k < 10; ++k) {
        const bool fin = (k == 9);
        __half2* gout = pp[k & 1];
        prop_k<<<grid, 256, 0, stream>>>(gin, g0t, gout, out, rowptr, cols,
                                         dinvv, b, N, E, nseq, fin ? 1 : 0);
        gin = gout;
    }
}

// Round 9
// 827.918 us; speedup vs baseline: 1.5799x; 1.1085x over previous
//
#include <hip/hip_runtime.h>
#include <hip/hip_fp16.h>
#include <math.h>

// Reverted to the r2 structure (full 128-B fp16 rows, 1 wave per dst row) —
// the 4x32B sliced design bottomed at ~75-80 us/step (half-line gathers
// double TA transactions; traffic win repaid in transaction count).
// r8 change vs r2: DEPTH-8 GATHER WINDOW. r2 kept ~4 gathers in flight
// (2.9 TB/s beyond-L2 fill, MSHR/MLP-bound); r8 issues up to 8 chunk
// gathers back-to-back per 64-edge group (wave-uniform nch guards), then
// consumes. Pre-scaled cols (col<<7) saves per-chunk address shifts.
// (Resubmission: previous round failed on container infra, not the kernel.)

#define BSH 8   // 256 dsts per bucket

typedef _Float16 h2_t __attribute__((ext_vector_type(2)));
union U16 { uint4 u; h2_t h[4]; };

// ---------------- small utils ----------------

__global__ void zero_i32(int* __restrict__ p, int n) {
    int i = blockIdx.x * blockDim.x + threadIdx.x;
    if (i < n) p[i] = 0;
}

// zero dummy row N (32 half2) of the three gather buffers
__global__ void zero_dummy(__half2* __restrict__ b0, __half2* __restrict__ b1,
                           __half2* __restrict__ b2, int N) {
    int t = threadIdx.x;
    if (t >= 96) return;
    __half2* b = (t < 32) ? b0 : (t < 64) ? b1 : b2;
    b[(size_t)N * 32 + (t & 31)] = __floats2half2_rn(0.f, 0.f);
}

// ---------------- bucket histogram (LDS-aggregated) ----------------

__global__ void __launch_bounds__(256) bucket_hist_k(const int* __restrict__ dst, int E,
                                                     int* __restrict__ bktcnt) {
    __shared__ int hist[400];
    int t = threadIdx.x;
    for (int i = t; i < 400; i += 256) hist[i] = 0;
    __syncthreads();
    int e0 = blockIdx.x * 4096 + t;
#pragma unroll
    for (int i = 0; i < 16; ++i) {
        int e = e0 + i * 256;
        if (e < E) atomicAdd(&hist[dst[e] >> BSH], 1);
    }
    __syncthreads();
    for (int b = t; b < 400; b += 256) {
        int c = hist[b];
        if (c > 0) atomicAdd(&bktcnt[b], c);
    }
}

// ---------------- 1-block scan of bucket totals -> bases + padded cursors ----------------

__global__ void bucket_scan_k(const int* __restrict__ bktcnt, int nb, int E,
                              int* __restrict__ bktbase, int* __restrict__ bktcur) {
    __shared__ int s[256];
    int t = threadIdx.x;
    int C = (nb + 255) / 256;            // <= 8
    int b0 = t * C;
    int loc[8]; int sum = 0;
    for (int i = 0; i < C; ++i) {
        int v = (b0 + i < nb) ? bktcnt[b0 + i] : 0;
        loc[i] = sum; sum += v;
    }
    s[t] = sum; __syncthreads();
    for (int off = 1; off < 256; off <<= 1) {
        int v = (t >= off) ? s[t - off] : 0;
        __syncthreads();
        s[t] += v;
        __syncthreads();
    }
    int excl = s[t] - sum;
    for (int i = 0; i < C; ++i)
        if (b0 + i < nb) {
            int e0 = excl + loc[i];
            bktbase[b0 + i] = e0;
            bktcur[(b0 + i) * 16] = e0;  // 64B-padded cursor
        }
    if (t == 0) bktbase[nb] = E;
}

// ---------------- bin edges by bucket (dst>>8), contiguous runs ----------------

__global__ void __launch_bounds__(256) binsort_k(const int* __restrict__ src,
                                                 const int* __restrict__ dst, int E,
                                                 int* __restrict__ bktcur,  // padded x16
                                                 unsigned* __restrict__ binned) {
    __shared__ int hist[400], gbase[400], lcur[400];
    int t = threadIdx.x;
    for (int i = t; i < 400; i += 256) { hist[i] = 0; lcur[i] = 0; }
    __syncthreads();

    int e0 = blockIdx.x * 4096 + t;
    unsigned rec[16]; int bk[16];
#pragma unroll
    for (int i = 0; i < 16; ++i) {
        int e = e0 + i * 256;
        if (e < E) {
            int s = src[e], d = dst[e];
            bk[i]  = d >> BSH;
            rec[i] = ((unsigned)s << BSH) | (unsigned)(d & 255);
            atomicAdd(&hist[bk[i]], 1);
        } else bk[i] = -1;
    }
    __syncthreads();
    for (int b = t; b < 400; b += 256) {
        int c = hist[b];
        if (c > 0) gbase[b] = atomicAdd(&bktcur[b * 16], c);
    }
    __syncthreads();
#pragma unroll
    for (int i = 0; i < 16; ++i) {
        if (bk[i] >= 0) {
            int loc = atomicAdd(&lcur[bk[i]], 1);
            binned[gbase[bk[i]] + loc] = rec[i];
        }
    }
}

// ---------------- per-bucket: degrees + rowptr + dinv + col scatter ----------------
// cols stored PRE-SCALED (col<<7 = byte offset of the 128-B row).

__global__ void __launch_bounds__(256) fill2_k(const unsigned* __restrict__ binned,
                                               const int* __restrict__ bktbase,
                                               int N, int E, int NB,
                                               int* __restrict__ rowptr,
                                               float* __restrict__ dinv,
                                               int* __restrict__ col) {
    __shared__ int cnt[256], excl[256], lcur[256];
    int b = blockIdx.x, t = threadIdx.x;
    int beg = bktbase[b], end = bktbase[b + 1];
    cnt[t] = 0;
    __syncthreads();
    for (int i = beg + t; i < end; i += 256)
        atomicAdd(&cnt[binned[i] & 255u], 1);
    __syncthreads();
    int v = cnt[t];
    excl[t] = v;
    __syncthreads();
    for (int off = 1; off < 256; off <<= 1) {
        int u = (t >= off) ? excl[t - off] : 0;
        __syncthreads();
        excl[t] += u;
        __syncthreads();
    }
    int ex = excl[t] - v;                // exclusive prefix within bucket
    lcur[t] = ex;
    int d = (b << BSH) + t;
    if (d < N) {
        rowptr[d] = beg + ex;            // coalesced
        dinv[d] = rsqrtf((float)(v + 1));  // +1 self-loop
    }
    if (b == NB - 1 && t == 0) rowptr[N] = E;
    __syncthreads();
    for (int i = beg + t; i < end; i += 256) {
        unsigned r = binned[i];
        int loc = atomicAdd(&lcur[r & 255u], 1);
        col[beg + loc] = (int)(r >> BSH) << 7;   // pre-scaled byte offset (128 B/row)
    }
}

// ---------------- g0 = x @ W : 64-row tile, W read from global (L1-resident) ----------------
// Emits TWO fp16 buffers: g0h = dinv[n]*g0[n] (gather state, +dummy row) and
// g0f = g0[n] (teleport term).

__global__ void __launch_bounds__(256) gemm_k(const float* __restrict__ x,
                                              const float* __restrict__ W,
                                              const float* __restrict__ dinv,
                                              __half2* __restrict__ g0f,
                                              __half2* __restrict__ g0h, int N) {
    __shared__ float xs[64 * 133];        // ~34 KB -> 4 blocks/CU
    int t = threadIdx.x;
    int n0 = blockIdx.x * 64;
    for (int f = t; f < 64 * 32; f += 256) {
        int r = f >> 5, c4 = f & 31;
        int n = n0 + r;
        float4 v = (n < N) ? ((const float4*)x)[(size_t)n * 32 + c4]
                           : make_float4(0.f, 0.f, 0.f, 0.f);
        float* dp = &xs[r * 133 + c4 * 4];
        dp[0] = v.x; dp[1] = v.y; dp[2] = v.z; dp[3] = v.w;
    }
    __syncthreads();
    int tr = t & 15, tc = t >> 4;
    int j0 = tr * 4, r0 = tc * 4;
    const float4* W4 = (const float4*)W;  // 32 KB total -> L1-resident
    float acc[4][4] = {};
#pragma unroll 8
    for (int k = 0; k < 128; ++k) {
        float4 wv = W4[k * 16 + tr];      // 256 B/k, broadcast across tc, L1 hit
#pragma unroll
        for (int i = 0; i < 4; ++i) {
            float xv = xs[(r0 + i) * 133 + k];
            acc[i][0] += xv * wv.x; acc[i][1] += xv * wv.y;
            acc[i][2] += xv * wv.z; acc[i][3] += xv * wv.w;
        }
    }
    int h0 = j0 >> 1;
#pragma unroll
    for (int i = 0; i < 4; ++i) {
        int n = n0 + r0 + i;
        if (n < N) {
            float dn = dinv[n];
            __half2* gf = &g0f[(size_t)n * 32 + h0];
            gf[0] = __floats2half2_rn(acc[i][0], acc[i][1]);
            gf[1] = __floats2half2_rn(acc[i][2], acc[i][3]);
            __half2* gp = &g0h[(size_t)n * 32 + h0];
            gp[0] = __floats2half2_rn(acc[i][0] * dn, acc[i][1] * dn);
            gp[1] = __floats2half2_rn(acc[i][2] * dn, acc[i][3] * dn);
        }
    }
}

// ---------------- propagation: 8 lanes per row, depth-8 gather window ----------------
// Wave = 1 dst row. lane = sub*8 + q: sub in [0,8) = edge slot, q in [0,8) =
// 16B segment of the 128 B fp16 row. Per 64-edge group: ONE coalesced cols
// load, then up to 8 chunk gathers ISSUED BACK-TO-BACK (nch guards are
// wave-uniform SALU branches), then 64 fdot2 consume. ~8 gathers in flight
// per wave (vs r2's ~4) -> deeper MLP on the beyond-L2 fill path.

__global__ void __launch_bounds__(256) prop_k(const __half2* __restrict__ gin,
                                              const __half2* __restrict__ g0f,
                                              __half2* __restrict__ gout,
                                              float* __restrict__ outf,
                                              const int* __restrict__ rowptr,
                                              const int* __restrict__ cols,
                                              const float* __restrict__ dinv,
                                              const float* __restrict__ bias,
                                              int N, int final_step) {
    int gw = (blockIdx.x * blockDim.x + threadIdx.x) >> 6;
    int lane = threadIdx.x & 63;
    if (gw >= N) return;
    int sub = lane >> 3;    // edge slot within the 8-group
    int q   = lane & 7;     // 16-B segment of the row
    unsigned qo = (unsigned)(q << 4);

    int beg = rowptr[gw], end = rowptr[gw + 1];
    int deg = end - beg;

    const char* gb = (const char*)gin;

    // hoisted epilogue operands (overlap with gather latency)
    float di = dinv[gw];
    U16 gi;  gi.u  = *(const uint4*)(gb + ((size_t)gw << 7) + qo);                 // self-loop
    U16 g0v; g0v.u = *(const uint4*)((const char*)g0f + ((size_t)gw << 7) + qo);   // teleport

    const h2_t SEL_LO = {(_Float16)1.f, (_Float16)0.f};
    const h2_t SEL_HI = {(_Float16)0.f, (_Float16)1.f};

    float a[8] = {};   // 8 f32 accumulators = this lane's 8 output columns
    const int DUMMY = N << 7;   // pre-scaled dummy row offset

    for (int base = 0; base < deg; base += 64) {
        int m = deg - base; if (m > 64) m = 64;
        int ci = cols[beg + base + (lane < m ? lane : 0)];   // 64 cols, one load (pre-scaled)
        int nch = (m + 7) >> 3;                              // 1..8 chunks, wave-uniform
        U16 v[8];
        // issue phase: all chunk gathers back-to-back
#pragma unroll
        for (int i = 0; i < 8; ++i) {
            if (i < nch) {
                int e8 = i * 8 + sub;
                int c = __shfl(ci, e8, 64);
                if (e8 >= m) c = DUMMY;                      // dummy zero row (L1-hot)
                v[i].u = *(const uint4*)(gb + (unsigned)(c | (int)qo));
            }
        }
        // consume phase
#pragma unroll
        for (int i = 0; i < 8; ++i) {
            if (i < nch) {
#pragma unroll
                for (int u = 0; u < 4; ++u) {
                    a[2 * u]     = __builtin_amdgcn_fdot2(v[i].h[u], SEL_LO, a[2 * u],     false);
                    a[2 * u + 1] = __builtin_amdgcn_fdot2(v[i].h[u], SEL_HI, a[2 * u + 1], false);
                }
            }
        }
    }

    // reduce across the 8 edge slots (lanes with equal q)
#pragma unroll
    for (int off = 8; off < 64; off <<= 1) {
#pragma unroll
        for (int u = 0; u < 8; ++u) a[u] += __shfl_xor(a[u], off, 64);
    }

    if (sub == 0) {   // 8 lanes, each owns cols [8q, 8q+8)
        float rr[8];
#pragma unroll
        for (int u = 0; u < 4; ++u) {
            float2 gf = __half22float2(*(__half2*)&gi.h[u]);
            float2 g0 = __half22float2(*(__half2*)&g0v.h[u]);
            rr[2 * u]     = 0.9f * di * (a[2 * u]     + gf.x) + 0.1f * g0.x;
            rr[2 * u + 1] = 0.9f * di * (a[2 * u + 1] + gf.y) + 0.1f * g0.y;
        }
        if (final_step) {
            float4 b0 = ((const float4*)bias)[2 * q];
            float4 b1 = ((const float4*)bias)[2 * q + 1];
            float4* op = (float4*)(outf + (size_t)gw * 64 + q * 8);
            op[0] = make_float4(rr[0] + b0.x, rr[1] + b0.y, rr[2] + b0.z, rr[3] + b0.w);
            op[1] = make_float4(rr[4] + b1.x, rr[5] + b1.y, rr[6] + b1.z, rr[7] + b1.w);
        } else {
            U16 o;
#pragma unroll
            for (int u = 0; u < 4; ++u) {
                __half2 h = __floats2half2_rn(di * rr[2 * u], di * rr[2 * u + 1]);
                o.h[u] = *(h2_t*)&h;
            }
            *(uint4*)((char*)gout + ((size_t)gw << 7) + qo) = o.u;
        }
    }
}

// ---------------- launch ----------------

extern "C" void kernel_launch(void* const* d_in, const int* in_sizes, int n_in,
                              void* d_out, int out_size, void* d_ws, size_t ws_size,
                              hipStream_t stream) {
    const float* x  = (const float*)d_in[0];
    const int*   ei = (const int*)d_in[1];
    const float* W  = (const float*)d_in[2];
    const float* b  = (const float*)d_in[3];
    float* out = (float*)d_out;

    const int N = in_sizes[0] / 128;
    const int E = in_sizes[1] / 2;
    const int* src = ei;
    const int* dst = ei + E;
    const int NB = (N + 255) >> BSH;     // buckets of 256 dsts

    char* w = (char*)d_ws;
    size_t off = 0;
    auto alloc = [&](size_t bytes) -> void* {
        void* p = w + off;
        off += (bytes + 255) & ~(size_t)255;
        return p;
    };
    const size_t fp16buf = (size_t)(N + 1) * 32 * sizeof(__half2);  // 128 B/row
    __half2*  g0h    = (__half2*) alloc(fp16buf);   // +1 dummy row
    __half2*  bufA   = (__half2*) alloc(fp16buf);
    __half2*  bufB   = (__half2*) alloc(fp16buf);
    __half2*  g0f    = (__half2*) alloc(fp16buf);
    int*      cols   = (int*)     alloc((size_t)E * 4);
    unsigned* binned = (unsigned*)alloc((size_t)E * 4);
    int*      rowptr = (int*)     alloc((size_t)(N + 1) * 4);
    int*      bktcnt = (int*)     alloc((size_t)NB * 4);
    int*      bktbase= (int*)     alloc((size_t)(NB + 1) * 4);
    int*      bktcur = (int*)     alloc((size_t)NB * 16 * 4);    // 64B-padded
    float*    dinvv  = (float*)   alloc((size_t)N * 4);

    const int nblkB = (E + 4095) / 4096;

    // ---- build dst-CSR: bucket hist -> scan -> binsort -> per-bucket fill ----
    zero_i32<<<(NB + 255) / 256, 256, 0, stream>>>(bktcnt, NB);
    bucket_hist_k<<<nblkB, 256, 0, stream>>>(dst, E, bktcnt);
    zero_dummy<<<1, 96, 0, stream>>>(g0h, bufA, bufB, N);
    bucket_scan_k<<<1, 256, 0, stream>>>(bktcnt, NB, E, bktbase, bktcur);
    binsort_k<<<nblkB, 256, 0, stream>>>(src, dst, E, bktcur, binned);
    fill2_k<<<NB, 256, 0, stream>>>(binned, bktbase, N, E, NB, rowptr, dinvv, cols);

    // g0 = x @ W (propagation commutes with the linear head)
    gemm_k<<<(N + 63) / 64, 256, 0, stream>>>(x, W, dinvv, g0f, g0h, N);

    // K = 10 APPNP steps, fp16 ping-pong; last step writes fp32 d_out (+bias)
    const int nblkP = (N * 64 + 255) / 256;
    const __half2* gin = g0h;
    __half2* pp[2] = {bufA, bufB};
    for (int k = 0; k < 10; ++k) {
        const bool fin = (k == 9);
        __half2* gout = pp[k & 1];
        prop_k<<<nblkP, 256, 0, stream>>>(gin, g0f, gout, out, rowptr, cols,
                                          dinvv, b, N, fin ? 1 : 0);
        gin = gout;
    }
}

// Round 10
// 753.758 us; speedup vs baseline: 1.7353x; 1.0984x over previous
//
#include <hip/hip_runtime.h>
#include <hip/hip_fp16.h>
#include <math.h>

// FINAL STRUCTURE: r2 prop loop restored (it sat at 98% of the ~3.4 TB/s
// beyond-L2 random-gather cap, measured robust across r1/r2/r9 structures).
// r9's depth-8 window REGRESSED (66.4 vs 57.8 us: VGPR pressure + vmcnt
// coupling); sliced designs (r3-r7) bottomed at 75-80 us (sub-line gathers).
// Kept micro-opts: pre-scaled cols (col<<7), fdot2 accumulate.
// gemm polish: float4 LDS reads over k (stride 132), float4 staging.

#define BSH 8   // 256 dsts per bucket

typedef _Float16 h2_t __attribute__((ext_vector_type(2)));
union U16 { uint4 u; h2_t h[4]; };

// ---------------- small utils ----------------

__global__ void zero_i32(int* __restrict__ p, int n) {
    int i = blockIdx.x * blockDim.x + threadIdx.x;
    if (i < n) p[i] = 0;
}

// zero dummy row N (32 half2) of the three gather buffers
__global__ void zero_dummy(__half2* __restrict__ b0, __half2* __restrict__ b1,
                           __half2* __restrict__ b2, int N) {
    int t = threadIdx.x;
    if (t >= 96) return;
    __half2* b = (t < 32) ? b0 : (t < 64) ? b1 : b2;
    b[(size_t)N * 32 + (t & 31)] = __floats2half2_rn(0.f, 0.f);
}

// ---------------- bucket histogram (LDS-aggregated) ----------------

__global__ void __launch_bounds__(256) bucket_hist_k(const int* __restrict__ dst, int E,
                                                     int* __restrict__ bktcnt) {
    __shared__ int hist[400];
    int t = threadIdx.x;
    for (int i = t; i < 400; i += 256) hist[i] = 0;
    __syncthreads();
    int e0 = blockIdx.x * 4096 + t;
#pragma unroll
    for (int i = 0; i < 16; ++i) {
        int e = e0 + i * 256;
        if (e < E) atomicAdd(&hist[dst[e] >> BSH], 1);
    }
    __syncthreads();
    for (int b = t; b < 400; b += 256) {
        int c = hist[b];
        if (c > 0) atomicAdd(&bktcnt[b], c);
    }
}

// ---------------- 1-block scan of bucket totals -> bases + padded cursors ----------------

__global__ void bucket_scan_k(const int* __restrict__ bktcnt, int nb, int E,
                              int* __restrict__ bktbase, int* __restrict__ bktcur) {
    __shared__ int s[256];
    int t = threadIdx.x;
    int C = (nb + 255) / 256;            // <= 8
    int b0 = t * C;
    int loc[8]; int sum = 0;
    for (int i = 0; i < C; ++i) {
        int v = (b0 + i < nb) ? bktcnt[b0 + i] : 0;
        loc[i] = sum; sum += v;
    }
    s[t] = sum; __syncthreads();
    for (int off = 1; off < 256; off <<= 1) {
        int v = (t >= off) ? s[t - off] : 0;
        __syncthreads();
        s[t] += v;
        __syncthreads();
    }
    int excl = s[t] - sum;
    for (int i = 0; i < C; ++i)
        if (b0 + i < nb) {
            int e0 = excl + loc[i];
            bktbase[b0 + i] = e0;
            bktcur[(b0 + i) * 16] = e0;  // 64B-padded cursor
        }
    if (t == 0) bktbase[nb] = E;
}

// ---------------- bin edges by bucket (dst>>8), contiguous runs ----------------

__global__ void __launch_bounds__(256) binsort_k(const int* __restrict__ src,
                                                 const int* __restrict__ dst, int E,
                                                 int* __restrict__ bktcur,  // padded x16
                                                 unsigned* __restrict__ binned) {
    __shared__ int hist[400], gbase[400], lcur[400];
    int t = threadIdx.x;
    for (int i = t; i < 400; i += 256) { hist[i] = 0; lcur[i] = 0; }
    __syncthreads();

    int e0 = blockIdx.x * 4096 + t;
    unsigned rec[16]; int bk[16];
#pragma unroll
    for (int i = 0; i < 16; ++i) {
        int e = e0 + i * 256;
        if (e < E) {
            int s = src[e], d = dst[e];
            bk[i]  = d >> BSH;
            rec[i] = ((unsigned)s << BSH) | (unsigned)(d & 255);
            atomicAdd(&hist[bk[i]], 1);
        } else bk[i] = -1;
    }
    __syncthreads();
    for (int b = t; b < 400; b += 256) {
        int c = hist[b];
        if (c > 0) gbase[b] = atomicAdd(&bktcur[b * 16], c);
    }
    __syncthreads();
#pragma unroll
    for (int i = 0; i < 16; ++i) {
        if (bk[i] >= 0) {
            int loc = atomicAdd(&lcur[bk[i]], 1);
            binned[gbase[bk[i]] + loc] = rec[i];
        }
    }
}

// ---------------- per-bucket: degrees + rowptr + dinv + col scatter ----------------
// cols stored PRE-SCALED (col<<7 = byte offset of the 128-B row).

__global__ void __launch_bounds__(256) fill2_k(const unsigned* __restrict__ binned,
                                               const int* __restrict__ bktbase,
                                               int N, int E, int NB,
                                               int* __restrict__ rowptr,
                                               float* __restrict__ dinv,
                                               int* __restrict__ col) {
    __shared__ int cnt[256], excl[256], lcur[256];
    int b = blockIdx.x, t = threadIdx.x;
    int beg = bktbase[b], end = bktbase[b + 1];
    cnt[t] = 0;
    __syncthreads();
    for (int i = beg + t; i < end; i += 256)
        atomicAdd(&cnt[binned[i] & 255u], 1);
    __syncthreads();
    int v = cnt[t];
    excl[t] = v;
    __syncthreads();
    for (int off = 1; off < 256; off <<= 1) {
        int u = (t >= off) ? excl[t - off] : 0;
        __syncthreads();
        excl[t] += u;
        __syncthreads();
    }
    int ex = excl[t] - v;                // exclusive prefix within bucket
    lcur[t] = ex;
    int d = (b << BSH) + t;
    if (d < N) {
        rowptr[d] = beg + ex;            // coalesced
        dinv[d] = rsqrtf((float)(v + 1));  // +1 self-loop
    }
    if (b == NB - 1 && t == 0) rowptr[N] = E;
    __syncthreads();
    for (int i = beg + t; i < end; i += 256) {
        unsigned r = binned[i];
        int loc = atomicAdd(&lcur[r & 255u], 1);
        col[beg + loc] = (int)(r >> BSH) << 7;   // pre-scaled byte offset (128 B/row)
    }
}

// ---------------- g0 = x @ W : 64-row tile, W from global (L1-resident) ----------------
// k-loop in chunks of 4 with float4 LDS reads (stride 132 -> 16-B aligned).
// Emits g0h = dinv[n]*g0[n] (gather state, +dummy row) and g0f = g0[n].

__global__ void __launch_bounds__(256) gemm_k(const float* __restrict__ x,
                                              const float* __restrict__ W,
                                              const float* __restrict__ dinv,
                                              __half2* __restrict__ g0f,
                                              __half2* __restrict__ g0h, int N) {
    __shared__ float xs[64 * 132];        // 33 KB -> 4 blocks/CU; stride 132 (%4==0)
    int t = threadIdx.x;
    int n0 = blockIdx.x * 64;
    for (int f = t; f < 64 * 32; f += 256) {
        int r = f >> 5, c4 = f & 31;
        int n = n0 + r;
        float4 v = (n < N) ? ((const float4*)x)[(size_t)n * 32 + c4]
                           : make_float4(0.f, 0.f, 0.f, 0.f);
        *(float4*)&xs[r * 132 + c4 * 4] = v;   // aligned float4 store
    }
    __syncthreads();
    int tr = t & 15, tc = t >> 4;
    int j0 = tr * 4, r0 = tc * 4;
    const float4* W4 = (const float4*)W;  // 32 KB total -> L1-resident
    float acc[4][4] = {};
#pragma unroll 4
    for (int k4 = 0; k4 < 32; ++k4) {
        float4 xv[4];
#pragma unroll
        for (int i = 0; i < 4; ++i)
            xv[i] = *(const float4*)&xs[(r0 + i) * 132 + k4 * 4];  // b128, bcast x16
        float4 wv[4];
#pragma unroll
        for (int kk = 0; kk < 4; ++kk)
            wv[kk] = W4[(k4 * 4 + kk) * 16 + tr];                  // L1 hit
#pragma unroll
        for (int kk = 0; kk < 4; ++kk) {
#pragma unroll
            for (int i = 0; i < 4; ++i) {
                float xvv = (kk == 0) ? xv[i].x : (kk == 1) ? xv[i].y
                          : (kk == 2) ? xv[i].z : xv[i].w;
                acc[i][0] += xvv * wv[kk].x; acc[i][1] += xvv * wv[kk].y;
                acc[i][2] += xvv * wv[kk].z; acc[i][3] += xvv * wv[kk].w;
            }
        }
    }
    int h0 = j0 >> 1;
#pragma unroll
    for (int i = 0; i < 4; ++i) {
        int n = n0 + r0 + i;
        if (n < N) {
            float dn = dinv[n];
            __half2* gf = &g0f[(size_t)n * 32 + h0];
            gf[0] = __floats2half2_rn(acc[i][0], acc[i][1]);
            gf[1] = __floats2half2_rn(acc[i][2], acc[i][3]);
            __half2* gp = &g0h[(size_t)n * 32 + h0];
            gp[0] = __floats2half2_rn(acc[i][0] * dn, acc[i][1] * dn);
            gp[1] = __floats2half2_rn(acc[i][2] * dn, acc[i][3] * dn);
        }
    }
}

// ---------------- propagation: r2 structure (8 lanes/row, interleaved chunks) ----------------
// Wave = 1 dst row. lane = sub*8 + q: sub in [0,8) = edge slot, q in [0,8) =
// 16-B segment of the 128-B fp16 row. Main loop: full 32-edge groups, no
// masking, load->consume interleaved per 8-edge chunk (compiler pipelines the
// 4 independent gathers). Tail: 8-edge steps masked to the dummy row.

__global__ void __launch_bounds__(256) prop_k(const __half2* __restrict__ gin,
                                              const __half2* __restrict__ g0f,
                                              __half2* __restrict__ gout,
                                              float* __restrict__ outf,
                                              const int* __restrict__ rowptr,
                                              const int* __restrict__ cols,
                                              const float* __restrict__ dinv,
                                              const float* __restrict__ bias,
                                              int N, int final_step) {
    int gw = (blockIdx.x * blockDim.x + threadIdx.x) >> 6;
    int lane = threadIdx.x & 63;
    if (gw >= N) return;
    int sub = lane >> 3;    // edge slot within the 8-group
    int q   = lane & 7;     // 16-B segment of the row
    int l32 = lane & 31;
    unsigned qo = (unsigned)(q << 4);

    int beg = rowptr[gw], end = rowptr[gw + 1];
    int deg = end - beg;

    const char* gb = (const char*)gin;

    // hoisted epilogue operands (overlap with gather latency)
    float di = dinv[gw];
    U16 gi;  gi.u  = *(const uint4*)(gb + ((size_t)gw << 7) + qo);                 // self-loop
    U16 g0v; g0v.u = *(const uint4*)((const char*)g0f + ((size_t)gw << 7) + qo);   // teleport

    const h2_t SEL_LO = {(_Float16)1.f, (_Float16)0.f};
    const h2_t SEL_HI = {(_Float16)0.f, (_Float16)1.f};

    float a[8] = {};   // 8 f32 accumulators = this lane's 8 output columns
    const int DUMMY = N << 7;   // pre-scaled dummy row offset

    int full = deg & ~31;
    for (int base = 0; base < full; base += 32) {
        int ci = cols[beg + base + l32];   // 32 cols, one load, all valid (pre-scaled)
#pragma unroll
        for (int i = 0; i < 4; ++i) {
            int c = __shfl(ci, i * 8 + sub, 64);
            U16 v; v.u = *(const uint4*)(gb + (unsigned)(c | (int)qo));
#pragma unroll
            for (int u = 0; u < 4; ++u) {
                a[2 * u]     = __builtin_amdgcn_fdot2(v.h[u], SEL_LO, a[2 * u],     false);
                a[2 * u + 1] = __builtin_amdgcn_fdot2(v.h[u], SEL_HI, a[2 * u + 1], false);
            }
        }
    }
    int m = deg - full;                    // 0..31 tail edges
    if (m > 0) {
        int ci = cols[beg + full + (l32 < m ? l32 : 0)];
#pragma unroll 4
        for (int i = 0; i * 8 < m; ++i) {
            int e = i * 8 + sub;
            int c = __shfl(ci, e, 64);
            if (e >= m) c = DUMMY;         // dummy zero row (L1-hot)
            U16 v; v.u = *(const uint4*)(gb + (unsigned)(c | (int)qo));
#pragma unroll
            for (int u = 0; u < 4; ++u) {
                a[2 * u]     = __builtin_amdgcn_fdot2(v.h[u], SEL_LO, a[2 * u],     false);
                a[2 * u + 1] = __builtin_amdgcn_fdot2(v.h[u], SEL_HI, a[2 * u + 1], false);
            }
        }
    }

    // reduce across the 8 edge slots (lanes with equal q)
#pragma unroll
    for (int off = 8; off < 64; off <<= 1) {
#pragma unroll
        for (int u = 0; u < 8; ++u) a[u] += __shfl_xor(a[u], off, 64);
    }

    if (sub == 0) {   // 8 lanes, each owns cols [8q, 8q+8)
        float rr[8];
#pragma unroll
        for (int u = 0; u < 4; ++u) {
            float2 gf = __half22float2(*(__half2*)&gi.h[u]);
            float2 g0 = __half22float2(*(__half2*)&g0v.h[u]);
            rr[2 * u]     = 0.9f * di * (a[2 * u]     + gf.x) + 0.1f * g0.x;
            rr[2 * u + 1] = 0.9f * di * (a[2 * u + 1] + gf.y) + 0.1f * g0.y;
        }
        if (final_step) {
            float4 b0 = ((const float4*)bias)[2 * q];
            float4 b1 = ((const float4*)bias)[2 * q + 1];
            float4* op = (float4*)(outf + (size_t)gw * 64 + q * 8);
            op[0] = make_float4(rr[0] + b0.x, rr[1] + b0.y, rr[2] + b0.z, rr[3] + b0.w);
            op[1] = make_float4(rr[4] + b1.x, rr[5] + b1.y, rr[6] + b1.z, rr[7] + b1.w);
        } else {
            U16 o;
#pragma unroll
            for (int u = 0; u < 4; ++u) {
                __half2 h = __floats2half2_rn(di * rr[2 * u], di * rr[2 * u + 1]);
                o.h[u] = *(h2_t*)&h;
            }
            *(uint4*)((char*)gout + ((size_t)gw << 7) + qo) = o.u;
        }
    }
}

// ---------------- launch ----------------

extern "C" void kernel_launch(void* const* d_in, const int* in_sizes, int n_in,
                              void* d_out, int out_size, void* d_ws, size_t ws_size,
                              hipStream_t stream) {
    const float* x  = (const float*)d_in[0];
    const int*   ei = (const int*)d_in[1];
    const float* W  = (const float*)d_in[2];
    const float* b  = (const float*)d_in[3];
    float* out = (float*)d_out;

    const int N = in_sizes[0] / 128;
    const int E = in_sizes[1] / 2;
    const int* src = ei;
    const int* dst = ei + E;
    const int NB = (N + 255) >> BSH;     // buckets of 256 dsts

    char* w = (char*)d_ws;
    size_t off = 0;
    auto alloc = [&](size_t bytes) -> void* {
        void* p = w + off;
        off += (bytes + 255) & ~(size_t)255;
        return p;
    };
    const size_t fp16buf = (size_t)(N + 1) * 32 * sizeof(__half2);  // 128 B/row
    __half2*  g0h    = (__half2*) alloc(fp16buf);   // +1 dummy row
    __half2*  bufA   = (__half2*) alloc(fp16buf);
    __half2*  bufB   = (__half2*) alloc(fp16buf);
    __half2*  g0f    = (__half2*) alloc(fp16buf);
    int*      cols   = (int*)     alloc((size_t)E * 4);
    unsigned* binned = (unsigned*)alloc((size_t)E * 4);
    int*      rowptr = (int*)     alloc((size_t)(N + 1) * 4);
    int*      bktcnt = (int*)     alloc((size_t)NB * 4);
    int*      bktbase= (int*)     alloc((size_t)(NB + 1) * 4);
    int*      bktcur = (int*)     alloc((size_t)NB * 16 * 4);    // 64B-padded
    float*    dinvv  = (float*)   alloc((size_t)N * 4);

    const int nblkB = (E + 4095) / 4096;

    // ---- build dst-CSR: bucket hist -> scan -> binsort -> per-bucket fill ----
    zero_i32<<<(NB + 255) / 256, 256, 0, stream>>>(bktcnt, NB);
    bucket_hist_k<<<nblkB, 256, 0, stream>>>(dst, E, bktcnt);
    zero_dummy<<<1, 96, 0, stream>>>(g0h, bufA, bufB, N);
    bucket_scan_k<<<1, 256, 0, stream>>>(bktcnt, NB, E, bktbase, bktcur);
    binsort_k<<<nblkB, 256, 0, stream>>>(src, dst, E, bktcur, binned);
    fill2_k<<<NB, 256, 0, stream>>>(binned, bktbase, N, E, NB, rowptr, dinvv, cols);

    // g0 = x @ W (propagation commutes with the linear head)
    gemm_k<<<(N + 63) / 64, 256, 0, stream>>>(x, W, dinvv, g0f, g0h, N);

    // K = 10 APPNP steps, fp16 ping-pong; last step writes fp32 d_out (+bias)
    const int nblkP = (N * 64 + 255) / 256;
    const __half2* gin = g0h;
    __half2* pp[2] = {bufA, bufB};
    for (int k = 0; k < 10; ++k) {
        const bool fin = (k == 9);
        __half2* gout = pp[k & 1];
        prop_k<<<nblkP, 256, 0, stream>>>(gin, g0f, gout, out, rowptr, cols,
                                          dinvv, b, N, fin ? 1 : 0);
        gin = gout;
    }
}